// Round 5
// baseline (980.132 us; speedup 1.0000x reference)
//
#include <hip/hip_runtime.h>
#include <hip/hip_bf16.h>
#include <math.h>

#define VOCAB 50257
#define NCLS 20
#define EDIM 64
#define HDIM 64
#define BATCH 128
#define TLEN 2048

typedef float v2f __attribute__((ext_vector_type(2)));

// Static device scratch: no dependence on ws_size, graph-capture safe.
__device__ float g_P[(size_t)2 * VOCAB * 192];   // 77.2 MB, input-projected vocab table (bias folded)
__device__ float g_feats[BATCH * 256];           // pooled features

__device__ __forceinline__ float fast_rcp(float x) { return __builtin_amdgcn_rcpf(x); }

__device__ __forceinline__ float fsigmoid(float x) {
    // 1/(1+exp(-x)); saturates correctly at +-inf
    return fast_rcp(1.f + __expf(-x));
}
__device__ __forceinline__ float ftanh(float x) {
    // 1 - 2/(exp(2x)+1); saturates correctly at +-inf
    float e = __expf(2.f * x);
    return 1.f - 2.f * fast_rcp(e + 1.f);
}

// ---------------- Kernel A: P[dir][v][g] = dot(emb[v], wih[dir][g]) + bih[dir][g] ----------------
__global__ __launch_bounds__(384) void precompute_P(
    const float* __restrict__ emb,
    const float* __restrict__ wih_f, const float* __restrict__ bih_f,
    const float* __restrict__ wih_b, const float* __restrict__ bih_b)
{
    const int t = threadIdx.x;          // 0..383 ; waves are uniform in (dir), contiguous in g
    const int dir = t / 192;
    const int g = t % 192;
    const float* wih = dir ? wih_b : wih_f;
    const float* bih = dir ? bih_b : bih_f;

    float w[64];
#pragma unroll
    for (int e = 0; e < 64; e += 4) {
        float4 v = *(const float4*)(wih + (size_t)g * 64 + e);
        w[e] = v.x; w[e + 1] = v.y; w[e + 2] = v.z; w[e + 3] = v.w;
    }
    const float bias = bih[g];
    float* Pd = g_P + (size_t)dir * VOCAB * 192;

    for (int v = blockIdx.x * 2; v < VOCAB; v += gridDim.x * 2) {
        const int v1ok = (v + 1 < VOCAB);
        const float4* e0 = (const float4*)(emb + (size_t)v * 64);            // wave-uniform -> scalar loads
        const float4* e1 = (const float4*)(emb + (size_t)(v1ok ? v + 1 : v) * 64);
        float a0 = bias, a1 = bias;
#pragma unroll
        for (int e4 = 0; e4 < 16; e4++) {
            float4 x = e0[e4];
            float4 y = e1[e4];
            a0 = fmaf(x.x, w[4 * e4 + 0], a0);
            a1 = fmaf(y.x, w[4 * e4 + 0], a1);
            a0 = fmaf(x.y, w[4 * e4 + 1], a0);
            a1 = fmaf(y.y, w[4 * e4 + 1], a1);
            a0 = fmaf(x.z, w[4 * e4 + 2], a0);
            a1 = fmaf(y.z, w[4 * e4 + 2], a1);
            a0 = fmaf(x.w, w[4 * e4 + 3], a0);
            a1 = fmaf(y.w, w[4 * e4 + 3], a1);
        }
        Pd[(size_t)v * 192 + g] = a0;
        if (v1ok) Pd[(size_t)(v + 1) * 192 + g] = a1;
    }
}

// ---------------- Kernel B: 3 waves per (dir,batch) sequence — wave = gate ----------------
// wave g (0=r,1=z,2=n), lane u owns whh row g*64+u: 64 weight floats/lane (~100 VGPR total).
// This removes the weight spilling that dominated rounds 0-4 (VGPR_Count pinned at 128 while
// the 1-wave layout needed ~240): no compiler vmem in the loop => the counted asm prefetch
// ring is finally valid. Each wave gathers only its own gate column of P: 1 dword/lane/step,
// depth-4 ring, s_waitcnt vmcnt(3) tied to the slot register ("+v": consumers data-depend).
// Cross-wave sync: raw s_barrier + asm lgkmcnt(0) ONLY (never __syncthreads: its vmcnt(0)
// drain would kill the ring). Wave2 combines: reads r,z from LDS, computes n, h, pooling.
// All arithmetic kept in the exact order of the verified kernel (absmax must stay 0.0).
__global__ __launch_bounds__(192, 1) void gru_seq(
    const int* __restrict__ tokens,
    const float* __restrict__ whh_f, const float* __restrict__ bhh_f,
    const float* __restrict__ whh_b, const float* __restrict__ bhh_b)
{
    const int tid = threadIdx.x;
    const int wid = tid >> 6;            // 0=r, 1=z, 2=n/combiner (wave-uniform)
    const int lane = tid & 63;           // hidden unit index
    const int blk = blockIdx.x;          // 0..255
    const int b = blk >> 1;
    const int dir = blk & 1;
    const float* whh = dir ? whh_b : whh_f;
    const float* bhh = dir ? bhh_b : bhh_f;
    // per-thread gather base: this gate's element for unit `lane`
    const float* Pd = g_P + (size_t)dir * VOCAB * 192 + wid * 64 + lane;

    __shared__ __align__(16) float h_lds[64];
    __shared__ float r_lds[64];
    __shared__ float z_lds[64];
    __shared__ __align__(16) int tok_lds[TLEN];

    // stage token row (8 KB) once, vectorized across 192 threads
    {
        const int4* src = (const int4*)(tokens + (size_t)b * TLEN);
        int4* dst = (int4*)tok_lds;
        for (int t = tid; t < TLEN / 4; t += 192) dst[t] = src[t];
    }

    // per-lane whh row for this wave's gate -> 32 v2f regs (64 VGPRs)
    v2f w[32];
    {
        const float* p = whh + (size_t)(wid * 64 + lane) * 64;
#pragma unroll
        for (int k = 0; k < 16; k++) {
            float4 a = *(const float4*)(p + 4 * k);
            w[2 * k] = (v2f){a.x, a.y};
            w[2 * k + 1] = (v2f){a.z, a.w};
        }
    }
    const float bias = bhh[wid * 64 + lane];

    if (wid == 2) h_lds[lane] = 0.f;
    float h = 0.f, sum = 0.f, mx = -INFINITY;   // h/sum/mx live in wave2 only
    __syncthreads();    // prologue-only: tok_lds + h_lds visible (vmcnt drain harmless here)

    // time mapping: step s -> tt = dir ? T-1-s : s
    auto tok_at = [&](int s) -> int {
        int ss = s < TLEN ? s : TLEN - 1;        // clamp for tail prefetches (values unused)
        return tok_lds[dir ? (TLEN - 1 - ss) : ss];
    };

    // depth-4 ring: 4 named regs per wave, defined ONLY by asm loads (1 load/step/wave)
    float x0, x1, x2, x3;
#define GRU_PRE(SL, D) \
    asm volatile("global_load_dword %0, %1, off" : "=v"(x##SL) : "v"(Pd + (size_t)tok_at(D) * 192))
    GRU_PRE(0, 0); GRU_PRE(1, 1); GRU_PRE(2, 2); GRU_PRE(3, 3);

#define GRU_STEP(SL, SB) do {                                                      \
        const int tN_ = tok_at((SB) + 4);   /* broadcast LDS read, off critical path */ \
        v2f a0 = {0.f, 0.f}, a1 = {0.f, 0.f};                                      \
        _Pragma("unroll")                                                          \
        for (int k = 0; k < 16; k++) {                                             \
            float4 h4 = *(const float4*)(h_lds + 4 * k);                           \
            v2f h01 = {h4.x, h4.y}, h23 = {h4.z, h4.w};                            \
            a0 = __builtin_elementwise_fma(h01, w[2 * k], a0);                     \
            a1 = __builtin_elementwise_fma(h23, w[2 * k + 1], a1);                 \
        }                                                                          \
        float hg = (a0.x + a0.y) + (a1.x + a1.y);                                  \
        if (wid != 2) {                                                            \
            /* retire oldest ring load; consumers tied to the waited reg */        \
            asm volatile("s_waitcnt vmcnt(3)" : "+v"(x##SL));                      \
            float g_ = fsigmoid(x##SL + hg + bias);                                \
            (wid == 0 ? r_lds : z_lds)[lane] = g_;                                 \
            asm volatile("global_load_dword %0, %1, off"                           \
                         : "=v"(x##SL) : "v"(Pd + (size_t)tN_ * 192));             \
        }                                                                          \
        asm volatile("s_waitcnt lgkmcnt(0)" ::: "memory");  /* r,z + all h-reads retired */ \
        __builtin_amdgcn_s_barrier();                        /* B: r,z visible to wave2 */  \
        __builtin_amdgcn_sched_barrier(0);                                         \
        if (wid == 2) {                                                            \
            asm volatile("s_waitcnt vmcnt(3)" : "+v"(x##SL));                      \
            float r_ = r_lds[lane];                                                \
            float z_ = z_lds[lane];                                                \
            float n_ = ftanh(x##SL + r_ * (hg + bias));                            \
            h = fmaf(z_, h - n_, n_);          /* (1-z)*n + z*h */                 \
            sum += h;                                                              \
            mx = fmaxf(mx, h);                                                     \
            h_lds[lane] = h;                                                       \
            asm volatile("global_load_dword %0, %1, off"                           \
                         : "=v"(x##SL) : "v"(Pd + (size_t)tN_ * 192));             \
        }                                                                          \
        asm volatile("s_waitcnt lgkmcnt(0)" ::: "memory");  /* h write retired */  \
        __builtin_amdgcn_s_barrier();                        /* C: h visible to all */      \
        __builtin_amdgcn_sched_barrier(0);                                         \
    } while (0)

    for (int s = 0; s < TLEN; s += 4) {
        GRU_STEP(0, s + 0);
        GRU_STEP(1, s + 1);
        GRU_STEP(2, s + 2);
        GRU_STEP(3, s + 3);
    }
    // drain the 4 tail prefetches per wave (clamped addresses, values dead)
    asm volatile("s_waitcnt vmcnt(0)" ::: "memory");

    // feats layout [b][256]: [mean_f | mean_b | max_f | max_b]
    if (wid == 2) {
        g_feats[b * 256 + dir * 64 + lane] = sum * (1.f / TLEN);
        g_feats[b * 256 + 128 + dir * 64 + lane] = mx;
    }
#undef GRU_PRE
#undef GRU_STEP
}

// ---------------- Kernel C: classifier  out = W2 @ gelu(W1 @ feats + b1) + b2 ----------------
__global__ __launch_bounds__(64) void classifier(
    const float* __restrict__ w1, const float* __restrict__ b1,
    const float* __restrict__ w2, const float* __restrict__ b2,
    float* __restrict__ out)
{
    const int b = blockIdx.x;
    const int i = threadIdx.x;
    __shared__ float f[256];
    __shared__ float hid[64];
    for (int c = i; c < 256; c += 64) f[c] = g_feats[b * 256 + c];
    __syncthreads();

    float acc = b1[i];
    const float* wrow = w1 + (size_t)i * 256;
#pragma unroll 16
    for (int c = 0; c < 256; c++) acc = fmaf(f[c], wrow[c], acc);
    // exact GELU: x * 0.5 * (1 + erf(x/sqrt(2)))
    hid[i] = acc * 0.5f * (1.f + erff(acc * 0.70710678118654752f));
    __syncthreads();

    if (i < NCLS) {
        float o = b2[i];
        const float* w2r = w2 + (size_t)i * 64;
#pragma unroll
        for (int j = 0; j < 64; j++) o = fmaf(hid[j], w2r[j], o);
        out[b * NCLS + i] = o;
    }
}

extern "C" void kernel_launch(void* const* d_in, const int* in_sizes, int n_in,
                              void* d_out, int out_size, void* d_ws, size_t ws_size,
                              hipStream_t stream) {
    const int*   tokens = (const int*)  d_in[0];
    const float* emb    = (const float*)d_in[1];
    const float* wih_f  = (const float*)d_in[2];
    const float* whh_f  = (const float*)d_in[3];
    const float* bih_f  = (const float*)d_in[4];
    const float* bhh_f  = (const float*)d_in[5];
    const float* wih_b  = (const float*)d_in[6];
    const float* whh_b  = (const float*)d_in[7];
    const float* bih_b  = (const float*)d_in[8];
    const float* bhh_b  = (const float*)d_in[9];
    const float* w1     = (const float*)d_in[10];
    const float* b1     = (const float*)d_in[11];
    const float* w2     = (const float*)d_in[12];
    const float* b2     = (const float*)d_in[13];
    float* out = (float*)d_out;

    precompute_P<<<4096, 384, 0, stream>>>(emb, wih_f, bih_f, wih_b, bih_b);
    gru_seq<<<2 * BATCH, 192, 0, stream>>>(tokens, whh_f, bhh_f, whh_b, bhh_b);
    classifier<<<BATCH, 64, 0, stream>>>(w1, b1, w2, b2, out);
}